// Round 18
// baseline (199.791 us; speedup 1.0000x reference)
//
#include <hip/hip_runtime.h>
#include <cstdint>
#include <cstddef>

#define S_LEN   2048
#define D_MODEL 1536
#define NH      24
#define HDIM    64
#define WINDOW  512
#define NANCH   4

typedef __attribute__((ext_vector_type(8))) short short8;
typedef __attribute__((ext_vector_type(4))) float floatx4;

#define ASYNC_COPY16(g, l) \
    __builtin_amdgcn_global_load_lds((const __attribute__((address_space(1))) uint32_t*)(g), \
                                     (__attribute__((address_space(3))) uint32_t*)(l), 16, 0, 0)

static __device__ __forceinline__ ushort f32_to_bf16(float f) {
    uint32_t u = __float_as_uint(f);
    uint32_t r = (u + 0x7FFFu + ((u >> 16) & 1u)) >> 16;
    return (ushort)r;
}

// ---------------- convert + prep fused: y<4 -> fp32->bf16; y==4 -> RoPE table + spike + sv-frags ----------------
__global__ __launch_bounds__(256) void convert_prep_kernel(
    const float* __restrict__ x,
    const float* __restrict__ wq, const float* __restrict__ wk, const float* __restrict__ wv,
    const uint8_t* __restrict__ raw,
    ushort* __restrict__ xb, ushort* __restrict__ wb,
    float* __restrict__ normf, float* __restrict__ cs, ushort* __restrict__ svb,
    int xq4, int wq4) {
    const int which = blockIdx.y;
    if (which == 4) {
        if (blockIdx.x < 256) {
            int idx = blockIdx.x * 256 + threadIdx.x;   // 65536 = s*32 + i
            int s = idx >> 5, i = idx & 31;
            float inv_freq = expf(-(float)i * 0.2878231366242557f); // ln(10000)/32
            float c, sn;
            sincosf((float)s * inv_freq, &sn, &c);
            cs[s * 64 + i]      = c;
            cs[s * 64 + 32 + i] = sn;
            return;
        }
        if (blockIdx.x != 256) return;
        __shared__ int sh[2];
        if (threadIdx.x == 0) { sh[0] = 0; sh[1] = 0; }
        __syncthreads();
        int f = 0, nz = 0;
        for (int i = threadIdx.x; i < S_LEN; i += 256) {
            uint8_t b = raw[i];
            if ((i & 3) == 3 && b == 0x3f) f++;          // 1.0f high byte
            if ((i & 3) != 0 && b != 0)    nz++;
        }
        if (f)  atomicAdd(&sh[0], f);
        if (nz) atomicAdd(&sh[1], nz);
        __syncthreads();
        const int mode = (sh[0] > 0) ? 2 : ((sh[1] > 0) ? 1 : 0);  // 2=f32 1=u8 0=i32
        for (int i = threadIdx.x; i < S_LEN; i += 256) {
            int v;
            if (mode == 2)      v = (((const float*)raw)[i] != 0.0f) ? 1 : 0;
            else if (mode == 1) v = raw[i] ? 1 : 0;
            else                v = (((const int*)raw)[i] != 0) ? 1 : 0;
            normf[i] = v ? 1.0f : 0.0f;
        }
        // sv B-fragments [kc 64][lane 64][8]: svb[kc][lane][j] = sv[kc*32 + (lane>>4)*8 + j]
        // (MFMA B-frag layout: lane n=l16 is the broadcast col, k = quad*8 + j)
        for (int idx = threadIdx.x; idx < 64 * 64 * 8; idx += 256) {
            int kc = idx >> 9, ln = (idx >> 3) & 63, j = idx & 7;
            int k = kc * 32 + ((ln >> 4) & 3) * 8 + j;
            int v;
            if (mode == 2)      v = (((const float*)raw)[k] != 0.0f) ? 1 : 0;
            else if (mode == 1) v = raw[k] ? 1 : 0;
            else                v = (((const int*)raw)[k] != 0) ? 1 : 0;
            svb[idx] = v ? (ushort)0x3F80 : (ushort)0;   // exact bf16 1.0 / 0.0
        }
        return;
    }
    const size_t w_elems = (size_t)D_MODEL * D_MODEL;
    const float* src; ushort* dst; int n4;
    if (which == 0)      { src = x;  dst = xb;               n4 = xq4; }
    else if (which == 1) { src = wq; dst = wb;               n4 = wq4; }
    else if (which == 2) { src = wk; dst = wb + w_elems;     n4 = wq4; }
    else                 { src = wv; dst = wb + 2 * w_elems; n4 = wq4; }
    int i = blockIdx.x * blockDim.x + threadIdx.x;
    if (i >= n4) return;
    float4 v = ((const float4*)src)[i];
    ushort4 o;
    o.x = f32_to_bf16(v.x);
    o.y = f32_to_bf16(v.y);
    o.z = f32_to_bf16(v.z);
    o.w = f32_to_bf16(v.w);
    ((ushort4*)dst)[i] = o;
}

// ---------------- QKV projection + fused RoPE, 128x128 tiles, BK=32, 8 waves ----------------
// (R6/R14/R17-proven structure; gemm <=44.5 on clean runs. ONLY delta vs R17:
// spike-folded V epilogue (V' = sv*V, ~10 epilogue VALU ops) enabling flash's
// MFMA-lsum.)
// Outputs fragment-major (contiguous lane*16B loads for attention):
//   z<2: Qf/Kf [h][tile16 (128)][plane (2)][lane (64)][8]  (roped; Q pre-scaled)
//   z=2: Vf    [h][kchunk32 (64)][j2 (4)][lane (64)][8]    (spike-folded)
__global__ __launch_bounds__(512) void gemm_qkv_kernel(
    const ushort* __restrict__ xb,   // [2048][1536] bf16
    const ushort* __restrict__ wb,   // [3][1536][1536] bf16
    const float*  __restrict__ cs,   // [2048][64] cos|sin table
    const float*  __restrict__ spikef, // [S] 0/1
    ushort* __restrict__ Qf, ushort* __restrict__ Kf, ushort* __restrict__ Vf)
{
    const int lb  = blockIdx.x;                 // 0..575
    const int idx = (lb & 7) * 72 + (lb >> 3);  // XCD-chunked (576 = 8*72 exactly)
    const int z   = idx / 192;                  // 0..2
    const int rem = idx % 192;
    const int n2  = rem >> 4;                   // 0..11 head-pair
    const int tm  = rem & 15;                   // 0..15 M tile
    const ushort* W = wb + (size_t)z * (D_MODEL * (size_t)D_MODEL);

    // buf b (b=0,1): A [128 rows][32 k] @ b*16384, B same @ b*16384+8192.
    // Epilogue: 2 wave-groups x 4 regions x 8192B from offset 0.
    __shared__ __align__(16) char smem[32768];

    const int tid  = threadIdx.x;
    const int wave = tid >> 6;                  // 0..7
    const int lane = tid & 63;

    // staging lane map: each wave stages 16 A-rows + 16 B-rows per tile.
    // row_local = wave*16 + (lane>>2); LDS slot chunk = lane&3; GLOBAL chunk
    // pre-swizzled so swizzled reads see right data while LDS write is linear.
    const int scol = ((lane & 3) ^ ((lane >> 3) & 3)) * 8;
    const int srow = wave * 16 + (lane >> 2);
    const ushort* gA = xb + (size_t)(tm * 128 + srow) * D_MODEL + scol;
    const ushort* gB = W  + (size_t)(n2 * 128 + srow) * D_MODEL + scol;

    const int wm = (wave >> 1) * 32;            // row offset of this wave's tile
    const int wn = (wave & 1) * 64;             // col offset (= head select)
    const int lrow  = lane & 15;
    const int quad  = lane >> 4;
    // read-side swizzle: chunk = quad ^ ((row>>1)&3); all row offsets (wm, 16i)
    // keep bits 1-2 = lrow's, so the term is (lrow>>1)&3 everywhere.
    const int xq = (quad ^ ((lrow >> 1) & 3)) * 8;

    floatx4 acc[2][4];
#pragma unroll
    for (int i = 0; i < 2; ++i)
#pragma unroll
        for (int j = 0; j < 4; ++j)
            acc[i][j] = (floatx4){0.f, 0.f, 0.f, 0.f};

    auto STAGE = [&](int b, int kt) {
        ushort* l = (ushort*)(smem + b * 16384) + wave * 512;
        const int ko = kt * 32;
        ASYNC_COPY16(gA + ko, l);            // A rows wave*16..+15
        ASYNC_COPY16(gB + ko, l + 4096);     // B rows wave*16..+15 (@ +8192B)
    };

    auto COMPUTE = [&](int b) {
        const ushort* Ah = (const ushort*)(smem + b * 16384);
        const ushort* Bh = Ah + 4096;
        short8 af[2], bf[4];
#pragma unroll
        for (int i = 0; i < 2; ++i) af[i] = *(const short8*)(&Ah[(wm + i * 16 + lrow) * 32 + xq]);
#pragma unroll
        for (int j = 0; j < 4; ++j) bf[j] = *(const short8*)(&Bh[(wn + j * 16 + lrow) * 32 + xq]);
#pragma unroll
        for (int i = 0; i < 2; ++i)
#pragma unroll
            for (int j = 0; j < 4; ++j)
                acc[i][j] = __builtin_amdgcn_mfma_f32_16x16x32_bf16(af[i], bf[j], acc[i][j], 0, 0, 0);
    };

    // prologue: stage k-tile 0 into buf 0
    STAGE(0, 0);
    __syncthreads();

    int cur = 0;
    for (int kt = 0; kt < D_MODEL / 32 - 1; ++kt) {
        STAGE(cur ^ 1, kt + 1);      // prefetch next tile (in flight across compute)
        COMPUTE(cur);
        __syncthreads();             // vmcnt(0)+lgkmcnt(0)+barrier: prefetch landed
        cur ^= 1;
    }
    COMPUTE(cur);                    // last tile, no prefetch

    __syncthreads();                 // all waves done reading; reuse smem as output stage

    const int r0 = (lane >> 4) * 4;
    const int c0 = lane & 15;
    const int l16  = lane & 15;
    const int h  = n2 * 2 + (wave & 1);         // this wave's head
    const int s0 = tm * 128 + wm;               // wave rows s0..s0+31

    // two wave-groups so each active wave gets an 8KB stage region
#pragma unroll
    for (int g = 0; g < 2; ++g) {
        if ((wave >> 2) == g) {
            ushort* Lw = (ushort*)(smem + (wave & 3) * 8192);
            if (z < 2) {
                const float qscale = (z == 0) ? 0.18033688011112042f : 1.0f;
                ushort* O = (z == 0) ? Qf : Kf;
                // fused RoPE into LDS stage [s_local 32][d 64] stride 72 (4608B)
#pragma unroll
                for (int i = 0; i < 2; ++i) {
#pragma unroll
                    for (int jj = 0; jj < 2; ++jj) {
                        const int cl = jj * 16 + c0;       // d0 in [0,32)
#pragma unroll
                        for (int r = 0; r < 4; ++r) {
                            const int row = s0 + i * 16 + r0 + r;
                            const float c  = cs[row * 64 + cl];
                            const float sn = cs[row * 64 + 32 + cl];
                            const float x0 = acc[i][jj][r];
                            const float x1 = acc[i][jj + 2][r];
                            const int rl = i * 16 + r0 + r;
                            Lw[rl * 72 + cl]      = f32_to_bf16((x0 * c - x1 * sn) * qscale);
                            Lw[rl * 72 + cl + 32] = f32_to_bf16((x1 * c + x0 * sn) * qscale);
                        }
                    }
                }
                // fragment-major store: [h][tile16][plane][lane][8]
                const int t16base = tm * 8 + (wave >> 1) * 2;
#pragma unroll
                for (int t = 0; t < 2; ++t) {
#pragma unroll
                    for (int p = 0; p < 2; ++p) {
                        uint4 v = *(uint4*)&Lw[(t * 16 + l16) * 72 + p * 32 + quad * 8];
                        *(uint4*)&O[((((size_t)h * 128 + t16base + t) * 2 + p) * 64 + lane) * 8] = v;
                    }
                }
            } else {
                // Vf: stage as [d 64][s_local 32] stride 40 (5120B), SPIKE-FOLDED
#pragma unroll
                for (int i = 0; i < 2; ++i) {
                    const float4 sp4 = *(const float4*)(spikef + s0 + i * 16 + r0);
#pragma unroll
                    for (int j = 0; j < 4; ++j) {
                        const int dl = j * 16 + c0;
                        ushort4 o;
                        o.x = f32_to_bf16(acc[i][j][0] * sp4.x);
                        o.y = f32_to_bf16(acc[i][j][1] * sp4.y);
                        o.z = f32_to_bf16(acc[i][j][2] * sp4.z);
                        o.w = f32_to_bf16(acc[i][j][3] * sp4.w);
                        *(ushort4*)&Lw[dl * 40 + i * 16 + r0] = o;
                    }
                }
                const int kc = tm * 4 + (wave >> 1);   // one 32-key chunk per wave
#pragma unroll
                for (int j2 = 0; j2 < 4; ++j2) {
                    uint4 v = *(uint4*)&Lw[(j2 * 16 + l16) * 40 + quad * 8];
                    *(uint4*)&Vf[((((size_t)h * 64 + kc) * 4 + j2) * 64 + lane) * 8] = v;
                }
            }
        }
        __syncthreads();
    }
}

// ---------------- flash attention: split-K, LPT order, MFMA lsum column ----------------
// R24: R17's LPT flash (proven 42.3us, best) + ONE delta: lsum on the MFMA
// pipe. Vf spike-folded upstream; lsum[q] = sum_k P[q,k]*sv[k] via one extra
// PV MFMA per 32-key chunk (B = svb frag). Removes sv-mul + lsum-add from the
// VALU inner loop (VALUBusy 38%, MFMA 5.6% idle) AND the epilogue
// shfl_xor/bpermute chain (Lacc lands row-aligned in accumulator layout).
// Never cleanly measured before (R7/R8/R12 were slow-pod confounded runs).
// Per-wave 5120B LDS region: P [16][72] in loop; 4x O-partial + 1x L-partial
// float4x64 after it.
__global__ __launch_bounds__(256) void flash_attn_kernel(
    const ushort* __restrict__ Qf,   // [H][128][2][64][8] bf16 roped, pre-scaled
    const ushort* __restrict__ Kf,   // [H][128][2][64][8] bf16 roped
    const ushort* __restrict__ Vf,   // [H][64][4][64][8] bf16, spike-folded
    const ushort* __restrict__ svb,  // [64][64][8] bf16 sv B-fragments
    const float* __restrict__ spikef,// [S] 0.0/1.0
    float* __restrict__ out)         // [S][1536]
{
    // XCD-aware remap: lb&7 = XCD slot; each XCD owns 3 whole heads
    const int lb   = blockIdx.x + (blockIdx.y << 7);  // 0..3071
    const int h    = (lb & 7) * 3 + ((lb >> 3) >> 7);
    const int qt16 = 127 - ((lb >> 3) & 127);         // LPT: longest (high qs) first
    const int qs   = qt16 * 16;
    const int tid  = threadIdx.x;
    const int wid  = tid >> 6;
    const int lane = tid & 63;
    const int quad = lane >> 4;
    const int l16  = lane & 15;

    __shared__ __align__(16) char smem[4 * 5120];
    char* wreg = smem + wid * 5120;
    ushort* Pst = (ushort*)wreg;     // P [q 16][k0..63], stride 72 (loop phase)

    // Q B-fragments: contiguous per-lane (same for all 4 waves)
    const ushort* Qp = Qf + (((size_t)h * 128 + qt16) * 2) * 512 + lane * 8;
    const short8 qf0 = *(const short8*)(Qp);
    const short8 qf1 = *(const short8*)(Qp + 512);

    const int q_lane = qs + l16;     // the query this lane's weights belong to

    floatx4 Oacc[4];
    floatx4 Lacc = (floatx4){0.f, 0.f, 0.f, 0.f};
#pragma unroll
    for (int j2 = 0; j2 < 4; ++j2) Oacc[j2] = (floatx4){0.f, 0.f, 0.f, 0.f};

    const int qtt = (qs + 15) >> 6;                   // diag tile (64-key granularity)
    const int lo = (qs > WINDOW ? qs - WINDOW : 0) >> 6;
    const int has_anchor = (lo > 0) ? 1 : 0;
    const int nt = (qtt - lo + 1) + has_anchor;

    const ushort* Kh  = Kf + ((size_t)h * 128) * 1024 + lane * 8;  // + t16*1024 + p*512
    const ushort* Vh  = Vf + ((size_t)h * 64) * 2048 + lane * 8;   // + kc*2048 + j2*512
    const ushort* svl = svb + lane * 8;                            // + kc*512

    for (int it = wid; it < nt; it += 4) {
        const int t = has_anchor ? (it == 0 ? 0 : lo + it - 1) : it;
        // mode: 0=interior 1=diag(k<=q) 2=window-edge 3=anchor(k<4)
        const int mode = (t == qtt) ? 1 : ((has_anchor && t == 0) ? 3 :
                         ((qs + 15 - t * 64 > WINDOW) ? 2 : 0));

        // ---- S^T = K . Q^T : 4 frags (one 64-key tile) ----
        floatx4 S[4];
#pragma unroll
        for (int f = 0; f < 4; ++f) {
            const int t16 = t * 4 + f;
            const ushort* Kp = Kh + (size_t)t16 * 1024;
            short8 kf0 = *(const short8*)(Kp);
            short8 kf1 = *(const short8*)(Kp + 512);
            floatx4 a = (floatx4){0.f, 0.f, 0.f, 0.f};
            a = __builtin_amdgcn_mfma_f32_16x16x32_bf16(kf0, qf0, a, 0, 0, 0);
            a = __builtin_amdgcn_mfma_f32_16x16x32_bf16(kf1, qf1, a, 0, 0, 0);
            S[f] = a;
        }

        // ---- mask (wave-uniform mode) + exp2; NO spike mul, NO lsum VALU ----
#pragma unroll
        for (int f = 0; f < 4; ++f) {
            const int kb = t * 64 + f * 16 + quad * 4;
#pragma unroll
            for (int r = 0; r < 4; ++r) {
                const int k = kb + r;
                const float e = exp2f(S[f][r]);
                bool keep;
                if (mode == 0)      keep = true;
                else if (mode == 1) keep = (k <= q_lane);
                else if (mode == 2) keep = ((k >= q_lane - WINDOW) || (k < NANCH));
                else                keep = (k < NANCH);
                S[f][r] = keep ? e : 0.f;
            }
        }

        // ---- pack P (bf16 truncation) -> LDS [q=l16][kcol], 4 x b64 ----
#pragma unroll
        for (int f = 0; f < 4; ++f) {
            uint32_t p01 = (__float_as_uint(S[f][0]) >> 16) | (__float_as_uint(S[f][1]) & 0xFFFF0000u);
            uint32_t p23 = (__float_as_uint(S[f][2]) >> 16) | (__float_as_uint(S[f][3]) & 0xFFFF0000u);
            uint2 pk; pk.x = p01; pk.y = p23;
            *(uint2*)(Pst + l16 * 72 + f * 16 + quad * 4) = pk;
        }

        // ---- P @ [V' | sv] : O += P V', lsum += P sv (extra MFMA column) ----
#pragma unroll
        for (int c = 0; c < 2; ++c) {
            const short8 pA = *(const short8*)(Pst + l16 * 72 + c * 32 + quad * 8);
            const int kc = t * 2 + c;
            const short8 sb = *(const short8*)(svl + (size_t)kc * 512);
            Lacc = __builtin_amdgcn_mfma_f32_16x16x32_bf16(pA, sb, Lacc, 0, 0, 0);
#pragma unroll
            for (int j2 = 0; j2 < 4; ++j2) {
                const short8 vf = *(const short8*)(Vh + (size_t)kc * 2048 + j2 * 512);
                Oacc[j2] = __builtin_amdgcn_mfma_f32_16x16x32_bf16(pA, vf, Oacc[j2], 0, 0, 0);
            }
        }
    }

    // ---- publish partials into this wave's region (reuses P space) ----
#pragma unroll
    for (int j2 = 0; j2 < 4; ++j2)
        *(floatx4*)(wreg + j2 * 1024 + lane * 16) = Oacc[j2];
    *(floatx4*)(wreg + 4096 + lane * 16) = Lacc;
    __syncthreads();

    // ---- tree-sum partials: wave w owns output slice j2 == w; lsum is
    //      row-aligned in accumulator layout (no cross-lane ops needed) ----
    floatx4 Os = (floatx4){0.f, 0.f, 0.f, 0.f};
    floatx4 Lt = (floatx4){0.f, 0.f, 0.f, 0.f};
#pragma unroll
    for (int w = 0; w < 4; ++w) {
        Os += *(const floatx4*)(smem + w * 5120 + wid * 1024 + lane * 16);
        Lt += *(const floatx4*)(smem + w * 5120 + 4096 + lane * 16);
    }

#pragma unroll
    for (int r = 0; r < 4; ++r) {
        const int qrow = qs + quad * 4 + r;
        const float linv = (Lt[r] > 0.f && spikef[qrow] != 0.f) ? (1.0f / Lt[r]) : 0.f;
        out[(size_t)qrow * D_MODEL + h * HDIM + wid * 16 + l16] = Os[r] * linv;
    }
}

extern "C" void kernel_launch(void* const* d_in, const int* in_sizes, int n_in,
                              void* d_out, int out_size, void* d_ws, size_t ws_size,
                              hipStream_t stream) {
    const float* x     = (const float*)d_in[0];
    const uint8_t* spike_raw = (const uint8_t*)d_in[1];
    const float* Wq    = (const float*)d_in[2];
    const float* Wk    = (const float*)d_in[3];
    const float* Wv    = (const float*)d_in[4];
    float* out = (float*)d_out;

    const size_t xb_elems = (size_t)S_LEN * D_MODEL;
    const size_t w_elems  = (size_t)D_MODEL * D_MODEL;
    const size_t hs_elems = (size_t)NH * S_LEN * HDIM;

    char* ws = (char*)d_ws;
    size_t off = 0;
    ushort* xb = (ushort*)(ws + off); off += xb_elems * 2;
    ushort* wb = (ushort*)(ws + off); off += 3 * w_elems * 2;
    ushort* Qf = (ushort*)(ws + off); off += hs_elems * 2;
    ushort* Kf = (ushort*)(ws + off); off += hs_elems * 2;
    ushort* Vf = (ushort*)(ws + off); off += hs_elems * 2;
    float*  cst = (float*)(ws + off); off += (size_t)S_LEN * 64 * 4;
    float* spike_f = (float*)(ws + off); off += S_LEN * 4;
    ushort* svb = (ushort*)(ws + off); off += (size_t)64 * 64 * 8 * 2;
    if (ws_size < off) return;

    // 0) converts + RoPE table + spike normalize + sv-fragments (one launch)
    {
        int xq4 = (int)(xb_elems / 4);
        int wq4 = (int)(w_elems / 4);
        convert_prep_kernel<<<dim3(3072, 5), 256, 0, stream>>>(
            x, Wq, Wk, Wv, spike_raw, xb, wb, spike_f, cst, svb, xq4, wq4);
    }

    // 1) QKV projections + fused RoPE (128x128 tiles, BK=32 dbuf, 8 waves/block)
    gemm_qkv_kernel<<<576, 512, 0, stream>>>(xb, wb, cst, spike_f, Qf, Kf, Vf);

    // 2) flash attention (split-K, LPT q-order, MFMA lsum, 3072 blocks)
    flash_attn_kernel<<<dim3(128, 24), 256, 0, stream>>>(Qf, Kf, Vf, svb, spike_f, out);
}

// Round 19
// 158.729 us; speedup vs baseline: 1.2587x; 1.2587x over previous
//
#include <hip/hip_runtime.h>
#include <cstdint>
#include <cstddef>

#define S_LEN   2048
#define D_MODEL 1536
#define NH      24
#define HDIM    64
#define WINDOW  512
#define NANCH   4

typedef __attribute__((ext_vector_type(8))) short short8;
typedef __attribute__((ext_vector_type(4))) float floatx4;

#define ASYNC_COPY16(g, l) \
    __builtin_amdgcn_global_load_lds((const __attribute__((address_space(1))) uint32_t*)(g), \
                                     (__attribute__((address_space(3))) uint32_t*)(l), 16, 0, 0)

static __device__ __forceinline__ ushort f32_to_bf16(float f) {
    uint32_t u = __float_as_uint(f);
    uint32_t r = (u + 0x7FFFu + ((u >> 16) & 1u)) >> 16;
    return (ushort)r;
}

// ---------------- convert + prep fused: y<4 -> fp32->bf16; y==4 -> RoPE table + spike ----------------
// (Exact R17 version — no svb tail.)
__global__ __launch_bounds__(256) void convert_prep_kernel(
    const float* __restrict__ x,
    const float* __restrict__ wq, const float* __restrict__ wk, const float* __restrict__ wv,
    const uint8_t* __restrict__ raw,
    ushort* __restrict__ xb, ushort* __restrict__ wb,
    float* __restrict__ normf, float* __restrict__ cs,
    int xq4, int wq4) {
    const int which = blockIdx.y;
    if (which == 4) {
        if (blockIdx.x < 256) {
            int idx = blockIdx.x * 256 + threadIdx.x;   // 65536 = s*32 + i
            int s = idx >> 5, i = idx & 31;
            float inv_freq = expf(-(float)i * 0.2878231366242557f); // ln(10000)/32
            float c, sn;
            sincosf((float)s * inv_freq, &sn, &c);
            cs[s * 64 + i]      = c;
            cs[s * 64 + 32 + i] = sn;
            return;
        }
        if (blockIdx.x != 256) return;
        __shared__ int sh[2];
        if (threadIdx.x == 0) { sh[0] = 0; sh[1] = 0; }
        __syncthreads();
        int f = 0, nz = 0;
        for (int i = threadIdx.x; i < S_LEN; i += 256) {
            uint8_t b = raw[i];
            if ((i & 3) == 3 && b == 0x3f) f++;          // 1.0f high byte
            if ((i & 3) != 0 && b != 0)    nz++;
        }
        if (f)  atomicAdd(&sh[0], f);
        if (nz) atomicAdd(&sh[1], nz);
        __syncthreads();
        const int mode = (sh[0] > 0) ? 2 : ((sh[1] > 0) ? 1 : 0);  // 2=f32 1=u8 0=i32
        for (int i = threadIdx.x; i < S_LEN; i += 256) {
            int v;
            if (mode == 2)      v = (((const float*)raw)[i] != 0.0f) ? 1 : 0;
            else if (mode == 1) v = raw[i] ? 1 : 0;
            else                v = (((const int*)raw)[i] != 0) ? 1 : 0;
            normf[i] = v ? 1.0f : 0.0f;
        }
        return;
    }
    const size_t w_elems = (size_t)D_MODEL * D_MODEL;
    const float* src; ushort* dst; int n4;
    if (which == 0)      { src = x;  dst = xb;               n4 = xq4; }
    else if (which == 1) { src = wq; dst = wb;               n4 = wq4; }
    else if (which == 2) { src = wk; dst = wb + w_elems;     n4 = wq4; }
    else                 { src = wv; dst = wb + 2 * w_elems; n4 = wq4; }
    int i = blockIdx.x * blockDim.x + threadIdx.x;
    if (i >= n4) return;
    float4 v = ((const float4*)src)[i];
    ushort4 o;
    o.x = f32_to_bf16(v.x);
    o.y = f32_to_bf16(v.y);
    o.z = f32_to_bf16(v.z);
    o.w = f32_to_bf16(v.w);
    ((ushort4*)dst)[i] = o;
}

// ---------------- QKV projection + fused RoPE, 128x128 tiles, BK=32, 8 waves ----------------
// EXACT R17 gemm. R18 ISOLATED a real code effect: the spike-folded V epilogue
// costs the WHOLE gemm 44.5 -> 61.4 us, perfectly correlated across 6 runs
// (with fold: R7/R8/R18 = 61.4; without: R6/R14/R17 <= 44.5) independent of
// pod state. NEVER spike-fold this epilogue.
// Outputs fragment-major (contiguous lane*16B loads for attention):
//   z<2: Qf/Kf [h][tile16 (128)][plane (2)][lane (64)][8]  (roped; Q pre-scaled)
//   z=2: Vf    [h][kchunk32 (64)][j2 (4)][lane (64)][8]
__global__ __launch_bounds__(512) void gemm_qkv_kernel(
    const ushort* __restrict__ xb,   // [2048][1536] bf16
    const ushort* __restrict__ wb,   // [3][1536][1536] bf16
    const float*  __restrict__ cs,   // [2048][64] cos|sin table
    ushort* __restrict__ Qf, ushort* __restrict__ Kf, ushort* __restrict__ Vf)
{
    const int lb  = blockIdx.x;                 // 0..575
    const int idx = (lb & 7) * 72 + (lb >> 3);  // XCD-chunked (576 = 8*72 exactly)
    const int z   = idx / 192;                  // 0..2
    const int rem = idx % 192;
    const int n2  = rem >> 4;                   // 0..11 head-pair
    const int tm  = rem & 15;                   // 0..15 M tile
    const ushort* W = wb + (size_t)z * (D_MODEL * (size_t)D_MODEL);

    // buf b (b=0,1): A [128 rows][32 k] @ b*16384, B same @ b*16384+8192.
    // Epilogue: 2 wave-groups x 4 regions x 8192B from offset 0.
    __shared__ __align__(16) char smem[32768];

    const int tid  = threadIdx.x;
    const int wave = tid >> 6;                  // 0..7
    const int lane = tid & 63;

    // staging lane map: each wave stages 16 A-rows + 16 B-rows per tile.
    // row_local = wave*16 + (lane>>2); LDS slot chunk = lane&3; GLOBAL chunk
    // pre-swizzled so swizzled reads see right data while LDS write is linear.
    const int scol = ((lane & 3) ^ ((lane >> 3) & 3)) * 8;
    const int srow = wave * 16 + (lane >> 2);
    const ushort* gA = xb + (size_t)(tm * 128 + srow) * D_MODEL + scol;
    const ushort* gB = W  + (size_t)(n2 * 128 + srow) * D_MODEL + scol;

    const int wm = (wave >> 1) * 32;            // row offset of this wave's tile
    const int wn = (wave & 1) * 64;             // col offset (= head select)
    const int lrow  = lane & 15;
    const int quad  = lane >> 4;
    // read-side swizzle: chunk = quad ^ ((row>>1)&3); all row offsets (wm, 16i)
    // keep bits 1-2 = lrow's, so the term is (lrow>>1)&3 everywhere.
    const int xq = (quad ^ ((lrow >> 1) & 3)) * 8;

    floatx4 acc[2][4];
#pragma unroll
    for (int i = 0; i < 2; ++i)
#pragma unroll
        for (int j = 0; j < 4; ++j)
            acc[i][j] = (floatx4){0.f, 0.f, 0.f, 0.f};

    auto STAGE = [&](int b, int kt) {
        ushort* l = (ushort*)(smem + b * 16384) + wave * 512;
        const int ko = kt * 32;
        ASYNC_COPY16(gA + ko, l);            // A rows wave*16..+15
        ASYNC_COPY16(gB + ko, l + 4096);     // B rows wave*16..+15 (@ +8192B)
    };

    auto COMPUTE = [&](int b) {
        const ushort* Ah = (const ushort*)(smem + b * 16384);
        const ushort* Bh = Ah + 4096;
        short8 af[2], bf[4];
#pragma unroll
        for (int i = 0; i < 2; ++i) af[i] = *(const short8*)(&Ah[(wm + i * 16 + lrow) * 32 + xq]);
#pragma unroll
        for (int j = 0; j < 4; ++j) bf[j] = *(const short8*)(&Bh[(wn + j * 16 + lrow) * 32 + xq]);
#pragma unroll
        for (int i = 0; i < 2; ++i)
#pragma unroll
            for (int j = 0; j < 4; ++j)
                acc[i][j] = __builtin_amdgcn_mfma_f32_16x16x32_bf16(af[i], bf[j], acc[i][j], 0, 0, 0);
    };

    // prologue: stage k-tile 0 into buf 0
    STAGE(0, 0);
    __syncthreads();

    int cur = 0;
    for (int kt = 0; kt < D_MODEL / 32 - 1; ++kt) {
        STAGE(cur ^ 1, kt + 1);      // prefetch next tile (in flight across compute)
        COMPUTE(cur);
        __syncthreads();             // vmcnt(0)+lgkmcnt(0)+barrier: prefetch landed
        cur ^= 1;
    }
    COMPUTE(cur);                    // last tile, no prefetch

    __syncthreads();                 // all waves done reading; reuse smem as output stage

    const int r0 = (lane >> 4) * 4;
    const int c0 = lane & 15;
    const int l16  = lane & 15;
    const int h  = n2 * 2 + (wave & 1);         // this wave's head
    const int s0 = tm * 128 + wm;               // wave rows s0..s0+31

    // two wave-groups so each active wave gets an 8KB stage region
#pragma unroll
    for (int g = 0; g < 2; ++g) {
        if ((wave >> 2) == g) {
            ushort* Lw = (ushort*)(smem + (wave & 3) * 8192);
            if (z < 2) {
                const float qscale = (z == 0) ? 0.18033688011112042f : 1.0f;
                ushort* O = (z == 0) ? Qf : Kf;
                // fused RoPE into LDS stage [s_local 32][d 64] stride 72 (4608B)
#pragma unroll
                for (int i = 0; i < 2; ++i) {
#pragma unroll
                    for (int jj = 0; jj < 2; ++jj) {
                        const int cl = jj * 16 + c0;       // d0 in [0,32)
#pragma unroll
                        for (int r = 0; r < 4; ++r) {
                            const int row = s0 + i * 16 + r0 + r;
                            const float c  = cs[row * 64 + cl];
                            const float sn = cs[row * 64 + 32 + cl];
                            const float x0 = acc[i][jj][r];
                            const float x1 = acc[i][jj + 2][r];
                            const int rl = i * 16 + r0 + r;
                            Lw[rl * 72 + cl]      = f32_to_bf16((x0 * c - x1 * sn) * qscale);
                            Lw[rl * 72 + cl + 32] = f32_to_bf16((x1 * c + x0 * sn) * qscale);
                        }
                    }
                }
                // fragment-major store: [h][tile16][plane][lane][8]
                const int t16base = tm * 8 + (wave >> 1) * 2;
#pragma unroll
                for (int t = 0; t < 2; ++t) {
#pragma unroll
                    for (int p = 0; p < 2; ++p) {
                        uint4 v = *(uint4*)&Lw[(t * 16 + l16) * 72 + p * 32 + quad * 8];
                        *(uint4*)&O[((((size_t)h * 128 + t16base + t) * 2 + p) * 64 + lane) * 8] = v;
                    }
                }
            } else {
                // Vf: stage as [d 64][s_local 32] stride 40 (5120B)
#pragma unroll
                for (int i = 0; i < 2; ++i) {
#pragma unroll
                    for (int j = 0; j < 4; ++j) {
                        const int dl = j * 16 + c0;
                        ushort4 o;
                        o.x = f32_to_bf16(acc[i][j][0]);
                        o.y = f32_to_bf16(acc[i][j][1]);
                        o.z = f32_to_bf16(acc[i][j][2]);
                        o.w = f32_to_bf16(acc[i][j][3]);
                        *(ushort4*)&Lw[dl * 40 + i * 16 + r0] = o;
                    }
                }
                const int kc = tm * 4 + (wave >> 1);   // one 32-key chunk per wave
#pragma unroll
                for (int j2 = 0; j2 < 4; ++j2) {
                    uint4 v = *(uint4*)&Lw[(j2 * 16 + l16) * 40 + quad * 8];
                    *(uint4*)&Vf[((((size_t)h * 64 + kc) * 4 + j2) * 64 + lane) * 8] = v;
                }
            }
        }
        __syncthreads();
    }
}

// ---------------- flash attention: split-K, LPT order, ones-MFMA lsum ----------------
// R25: R17's LPT flash (proven 42.3us, best total 169.0) + ONE delta: lsum on
// the MFMA pipe via a CONSTANT all-ones B-fragment (bf16 1.0 broadcast). P
// keeps the sv multiply (so V and gemm stay untouched — R18 proved spike-
// folding the gemm epilogue poisons it 44.5->61.4us). Removes the scalar
// lsum+=w from the VALU loop AND the epilogue shfl_xor x2 + ds_bpermute x4
// chain (Lacc = mfma(P, ones) lands row-aligned: Lt[r] = sum_k P[q,k], with
// sv already inside P). No svb buffer, zero extra memory traffic.
// Per-wave 5120B LDS region: P [16][72] in loop; 4x O-partial + 1x L-partial
// float4x64 after it.
__global__ __launch_bounds__(256) void flash_attn_kernel(
    const ushort* __restrict__ Qf,   // [H][128][2][64][8] bf16 roped, pre-scaled
    const ushort* __restrict__ Kf,   // [H][128][2][64][8] bf16 roped
    const ushort* __restrict__ Vf,   // [H][64][4][64][8] bf16
    const float* __restrict__ spikef,// [S] 0.0/1.0
    float* __restrict__ out)         // [S][1536]
{
    // XCD-aware remap: lb&7 = XCD slot; each XCD owns 3 whole heads
    const int lb   = blockIdx.x + (blockIdx.y << 7);  // 0..3071
    const int h    = (lb & 7) * 3 + ((lb >> 3) >> 7);
    const int qt16 = 127 - ((lb >> 3) & 127);         // LPT: longest (high qs) first
    const int qs   = qt16 * 16;
    const int tid  = threadIdx.x;
    const int wid  = tid >> 6;
    const int lane = tid & 63;
    const int quad = lane >> 4;
    const int l16  = lane & 15;

    __shared__ __align__(16) char smem[4 * 5120];
    char* wreg = smem + wid * 5120;
    ushort* Pst = (ushort*)wreg;     // P [q 16][k0..63], stride 72 (loop phase)

    // Q B-fragments: contiguous per-lane (same for all 4 waves)
    const ushort* Qp = Qf + (((size_t)h * 128 + qt16) * 2) * 512 + lane * 8;
    const short8 qf0 = *(const short8*)(Qp);
    const short8 qf1 = *(const short8*)(Qp + 512);

    const int q_lane = qs + l16;     // the query this lane's weights belong to

    // constant all-ones bf16 B-fragment for the lsum MFMA column
    const short8 ones = {(short)0x3F80, (short)0x3F80, (short)0x3F80, (short)0x3F80,
                         (short)0x3F80, (short)0x3F80, (short)0x3F80, (short)0x3F80};

    floatx4 Oacc[4];
    floatx4 Lacc = (floatx4){0.f, 0.f, 0.f, 0.f};
#pragma unroll
    for (int j2 = 0; j2 < 4; ++j2) Oacc[j2] = (floatx4){0.f, 0.f, 0.f, 0.f};

    const int qtt = (qs + 15) >> 6;                   // diag tile (64-key granularity)
    const int lo = (qs > WINDOW ? qs - WINDOW : 0) >> 6;
    const int has_anchor = (lo > 0) ? 1 : 0;
    const int nt = (qtt - lo + 1) + has_anchor;

    const ushort* Kh = Kf + ((size_t)h * 128) * 1024 + lane * 8;   // + t16*1024 + p*512
    const ushort* Vh = Vf + ((size_t)h * 64) * 2048 + lane * 8;    // + kc*2048 + j2*512

    for (int it = wid; it < nt; it += 4) {
        const int t = has_anchor ? (it == 0 ? 0 : lo + it - 1) : it;
        // mode: 0=interior 1=diag(k<=q) 2=window-edge 3=anchor(k<4)
        const int mode = (t == qtt) ? 1 : ((has_anchor && t == 0) ? 3 :
                         ((qs + 15 - t * 64 > WINDOW) ? 2 : 0));

        // ---- S^T = K . Q^T : 4 frags (one 64-key tile) ----
        floatx4 S[4];
        float4 sp[4];
#pragma unroll
        for (int f = 0; f < 4; ++f) {
            const int t16 = t * 4 + f;
            const ushort* Kp = Kh + (size_t)t16 * 1024;
            short8 kf0 = *(const short8*)(Kp);
            short8 kf1 = *(const short8*)(Kp + 512);
            sp[f] = *(const float4*)(spikef + t16 * 16 + quad * 4);
            floatx4 a = (floatx4){0.f, 0.f, 0.f, 0.f};
            a = __builtin_amdgcn_mfma_f32_16x16x32_bf16(kf0, qf0, a, 0, 0, 0);
            a = __builtin_amdgcn_mfma_f32_16x16x32_bf16(kf1, qf1, a, 0, 0, 0);
            S[f] = a;
        }

        // ---- mask (wave-uniform mode) + exp2 + sv mul; NO scalar lsum ----
#pragma unroll
        for (int f = 0; f < 4; ++f) {
            const int kb = t * 64 + f * 16 + quad * 4;
#pragma unroll
            for (int r = 0; r < 4; ++r) {
                const int k = kb + r;
                float v;
                if (mode == 0)      v = 1.f;
                else if (mode == 1) v = (k <= q_lane) ? 1.f : 0.f;
                else if (mode == 2) v = ((k >= q_lane - WINDOW) || (k < NANCH)) ? 1.f : 0.f;
                else                v = (k < NANCH) ? 1.f : 0.f;
                const float sv = (r == 0) ? sp[f].x : (r == 1) ? sp[f].y : (r == 2) ? sp[f].z : sp[f].w;
                S[f][r] = exp2f(S[f][r]) * v * sv;
            }
        }

        // ---- pack P (bf16 truncation) -> LDS [q=l16][kcol], 4 x b64 ----
#pragma unroll
        for (int f = 0; f < 4; ++f) {
            uint32_t p01 = (__float_as_uint(S[f][0]) >> 16) | (__float_as_uint(S[f][1]) & 0xFFFF0000u);
            uint32_t p23 = (__float_as_uint(S[f][2]) >> 16) | (__float_as_uint(S[f][3]) & 0xFFFF0000u);
            uint2 pk; pk.x = p01; pk.y = p23;
            *(uint2*)(Pst + l16 * 72 + f * 16 + quad * 4) = pk;
        }

        // ---- P @ [V | 1] : O += P V, lsum += P·1 (extra MFMA column) ----
#pragma unroll
        for (int c = 0; c < 2; ++c) {
            const short8 pA = *(const short8*)(Pst + l16 * 72 + c * 32 + quad * 8);
            const int kc = t * 2 + c;
            Lacc = __builtin_amdgcn_mfma_f32_16x16x32_bf16(pA, ones, Lacc, 0, 0, 0);
#pragma unroll
            for (int j2 = 0; j2 < 4; ++j2) {
                const short8 vf = *(const short8*)(Vh + (size_t)kc * 2048 + j2 * 512);
                Oacc[j2] = __builtin_amdgcn_mfma_f32_16x16x32_bf16(pA, vf, Oacc[j2], 0, 0, 0);
            }
        }
    }

    // ---- publish partials into this wave's region (reuses P space) ----
#pragma unroll
    for (int j2 = 0; j2 < 4; ++j2)
        *(floatx4*)(wreg + j2 * 1024 + lane * 16) = Oacc[j2];
    *(floatx4*)(wreg + 4096 + lane * 16) = Lacc;
    __syncthreads();

    // ---- tree-sum partials: wave w owns output slice j2 == w; lsum is
    //      row-aligned in accumulator layout (no cross-lane ops needed) ----
    floatx4 Os = (floatx4){0.f, 0.f, 0.f, 0.f};
    floatx4 Lt = (floatx4){0.f, 0.f, 0.f, 0.f};
#pragma unroll
    for (int w = 0; w < 4; ++w) {
        Os += *(const floatx4*)(smem + w * 5120 + wid * 1024 + lane * 16);
        Lt += *(const floatx4*)(smem + w * 5120 + 4096 + lane * 16);
    }

#pragma unroll
    for (int r = 0; r < 4; ++r) {
        const int qrow = qs + quad * 4 + r;
        const float linv = (Lt[r] > 0.f && spikef[qrow] != 0.f) ? (1.0f / Lt[r]) : 0.f;
        out[(size_t)qrow * D_MODEL + h * HDIM + wid * 16 + l16] = Os[r] * linv;
    }
}

extern "C" void kernel_launch(void* const* d_in, const int* in_sizes, int n_in,
                              void* d_out, int out_size, void* d_ws, size_t ws_size,
                              hipStream_t stream) {
    const float* x     = (const float*)d_in[0];
    const uint8_t* spike_raw = (const uint8_t*)d_in[1];
    const float* Wq    = (const float*)d_in[2];
    const float* Wk    = (const float*)d_in[3];
    const float* Wv    = (const float*)d_in[4];
    float* out = (float*)d_out;

    const size_t xb_elems = (size_t)S_LEN * D_MODEL;
    const size_t w_elems  = (size_t)D_MODEL * D_MODEL;
    const size_t hs_elems = (size_t)NH * S_LEN * HDIM;

    char* ws = (char*)d_ws;
    size_t off = 0;
    ushort* xb = (ushort*)(ws + off); off += xb_elems * 2;
    ushort* wb = (ushort*)(ws + off); off += 3 * w_elems * 2;
    ushort* Qf = (ushort*)(ws + off); off += hs_elems * 2;
    ushort* Kf = (ushort*)(ws + off); off += hs_elems * 2;
    ushort* Vf = (ushort*)(ws + off); off += hs_elems * 2;
    float*  cst = (float*)(ws + off); off += (size_t)S_LEN * 64 * 4;
    float* spike_f = (float*)(ws + off); off += S_LEN * 4;
    if (ws_size < off) return;

    // 0) converts + RoPE table + spike normalize (one launch)
    {
        int xq4 = (int)(xb_elems / 4);
        int wq4 = (int)(w_elems / 4);
        convert_prep_kernel<<<dim3(3072, 5), 256, 0, stream>>>(
            x, Wq, Wk, Wv, spike_raw, xb, wb, spike_f, cst, xq4, wq4);
    }

    // 1) QKV projections + fused RoPE (128x128 tiles, BK=32 dbuf, 8 waves/block)
    gemm_qkv_kernel<<<576, 512, 0, stream>>>(xb, wb, cst, Qf, Kf, Vf);

    // 2) flash attention (split-K, LPT q-order, ones-MFMA lsum, 3072 blocks)
    flash_attn_kernel<<<dim3(128, 24), 256, 0, stream>>>(Qf, Kf, Vf, spike_f, out);
}